// Round 7
// baseline (1496.974 us; speedup 1.0000x reference)
//
#include <hip/hip_runtime.h>

#define NFEAT 128
#define BSHIFT 7
#define BNODES 128            // dst nodes per bucket (1 << BSHIFT)
#define NBMAX 1024            // max buckets
#define CHUNK 8192            // edges per counting/partition block
#define EBUF_CAP 3072         // per-bucket edge capacity (mean ~2046, sigma ~45)
#define TSHIFT 11             // src-tile = src >> 11 (2048 rows = 512 KB bf16)
#define NTILES 64

typedef __attribute__((ext_vector_type(8))) short bf16x8;
typedef __attribute__((ext_vector_type(4))) float f32x4;

__device__ inline unsigned short f2bf(float f) {            // RNE
    unsigned u = __float_as_uint(f);
    u += 0x7FFF + ((u >> 16) & 1);
    return (unsigned short)(u >> 16);
}
__device__ inline float bf2f(unsigned short h) {
    return __uint_as_float((unsigned)h << 16);
}

// ---------------- fused: out-degree histogram + per-bucket edge counts ----------------
__global__ __launch_bounds__(256)
void edge_count_kernel(const int* __restrict__ src, const int* __restrict__ dst, int E,
                       int* __restrict__ out_deg, int* __restrict__ bucket_cnt, int NB) {
    __shared__ int cnt[NBMAX];
    for (int i = threadIdx.x; i < NB; i += 256) cnt[i] = 0;
    __syncthreads();
    int base = blockIdx.x * CHUNK;
    int end = min(base + CHUNK, E);
    for (int j = base + threadIdx.x; j < end; j += 256) {
        atomicAdd(&out_deg[src[j]], 1);
        atomicAdd(&cnt[dst[j] >> BSHIFT], 1);
    }
    __syncthreads();
    for (int i = threadIdx.x; i < NB; i += 256)
        if (cnt[i]) atomicAdd(&bucket_cnt[i], cnt[i]);
}

// ---------------- scan bucket counts -> base & cursor (single block, 1024 thr) ----------------
__global__ __launch_bounds__(1024)
void bucket_scan_kernel(const int* __restrict__ bucket_cnt,
                        int* __restrict__ bucket_base,
                        int* __restrict__ bucket_cursor, int NB) {
    __shared__ int sa[1024], sb[1024];
    int tid = threadIdx.x;
    int v = (tid < NB) ? bucket_cnt[tid] : 0;
    sa[tid] = v;
    __syncthreads();
    int* s = sa; int* t = sb;
    for (int d = 1; d < 1024; d <<= 1) {
        t[tid] = s[tid] + (tid >= d ? s[tid - d] : 0);
        __syncthreads();
        int* tmp = s; s = t; t = tmp;
    }
    int incl = s[tid];
    int excl = incl - v;
    if (tid < NB) { bucket_base[tid] = excl; bucket_cursor[tid] = excl; }
    if (tid == 1023) bucket_base[NB] = incl;   // = E
}

// ---------------- partition edges into dst-bucket-ordered packed array ----------------
// packed = ((dst & 127) << 17) | src   (src < 2^17)
__global__ __launch_bounds__(256)
void partition_kernel(const int* __restrict__ src, const int* __restrict__ dst, int E,
                      int* __restrict__ bucket_cursor, int* __restrict__ packed, int NB) {
    __shared__ int cnt[NBMAX];
    for (int i = threadIdx.x; i < NB; i += 256) cnt[i] = 0;
    __syncthreads();
    int base = blockIdx.x * CHUNK;
    int end = min(base + CHUNK, E);
    for (int j = base + threadIdx.x; j < end; j += 256)
        atomicAdd(&cnt[dst[j] >> BSHIFT], 1);
    __syncthreads();
    for (int i = threadIdx.x; i < NB; i += 256) {
        int c = cnt[i];
        cnt[i] = c ? atomicAdd(&bucket_cursor[i], c) : 0;   // becomes global run base
    }
    __syncthreads();
    for (int j = base + threadIdx.x; j < end; j += 256) {
        int d = dst[j];
        int b = d >> BSHIFT;
        int pos = atomicAdd(&cnt[b], 1);
        packed[pos] = ((d & (BNODES - 1)) << 17) | src[j];
    }
}

// ---------------- xh = bf16(x * onorm); tail threads transpose-cast W ----------------
__global__ __launch_bounds__(256)
void cast_kernel(const float* __restrict__ x, const int* __restrict__ out_deg,
                 unsigned short* __restrict__ xh,
                 const float* __restrict__ W, unsigned short* __restrict__ Wt, int N) {
    int t = blockIdx.x * 256 + threadIdx.x;
    int total = N * (NFEAT / 4);
    if (t < total) {
        int row = t >> 5;                       // 32 chunks per row
        float sc = rsqrtf((float)max(out_deg[row], 1));
        float4 v = reinterpret_cast<const float4*>(x)[t];
        ushort4 o;
        o.x = f2bf(v.x * sc); o.y = f2bf(v.y * sc);
        o.z = f2bf(v.z * sc); o.w = f2bf(v.w * sc);
        reinterpret_cast<ushort4*>(xh)[t] = o;
    } else {
        int i = t - total;
        if (i < NFEAT * NFEAT) {
            int col = i >> 7, k = i & 127;
            Wt[i] = f2bf(W[k * NFEAT + col]);   // Wt[col][k]
        }
    }
}

// ---------------- per-bucket aggregation: src-tile-sorted sweep into LDS f32 accumulators ----
// One block (512 thr) per 128-dst-node bucket. Edges counting-sorted by src>>11 in LDS,
// then streamed in src order: gather xh row (L2/L3-hot window), LDS-atomic accumulate.
// Writes inorm-scaled bf16 rows STRIDED into aggh (node slot = 512 B, payload first 256 B).
__global__ __launch_bounds__(512)
void bucket_agg_kernel(const unsigned short* __restrict__ xh, const int* __restrict__ packed,
                       const int* __restrict__ bucket_base,
                       unsigned short* __restrict__ aggh, int N) {
    __shared__ float accum[BNODES][NFEAT];     // 64 KiB
    __shared__ int ebuf[EBUF_CAP];             // 12 KiB (src-sorted packed edges)
    __shared__ int ndeg[BNODES];
    __shared__ int tileh[NTILES];
    __shared__ int tilecur[NTILES];

    int bkt = blockIdx.x;
    int beg = bucket_base[bkt];
    int end = bucket_base[bkt + 1];
    int cnt = end - beg;
    int tid = threadIdx.x;
    int node0 = bkt << BSHIFT;

    for (int i = tid; i < BNODES * NFEAT / 4; i += 512)
        reinterpret_cast<float4*>(&accum[0][0])[i] = make_float4(0.f, 0.f, 0.f, 0.f);
    for (int i = tid; i < BNODES; i += 512) ndeg[i] = 0;
    if (tid < NTILES) tileh[tid] = 0;
    __syncthreads();

    // histograms: per-node in-degree + per-src-tile counts
    for (int i = beg + tid; i < end; i += 512) {
        int p = packed[i];
        atomicAdd(&ndeg[p >> 17], 1);
        atomicAdd(&tileh[(p & 0x1FFFF) >> TSHIFT], 1);
    }
    __syncthreads();

    bool sorted = (cnt <= EBUF_CAP);
    if (sorted) {
        if (tid == 0) {                         // serial exclusive scan over 64 tiles
            int run = 0;
            #pragma unroll
            for (int tt = 0; tt < NTILES; ++tt) { int c = tileh[tt]; tilecur[tt] = run; run += c; }
        }
        __syncthreads();
        for (int i = beg + tid; i < end; i += 512) {
            int p = packed[i];
            int pos = atomicAdd(&tilecur[(p & 0x1FFFF) >> TSHIFT], 1);
            ebuf[pos] = p;
        }
        __syncthreads();
    }

    // sweep edges in src order: 8 waves, 8 consecutive edges per wave per iter (window = 64)
    const ushort4* xr = reinterpret_cast<const ushort4*>(xh);
    int wv = tid >> 6;
    int lane = tid & 63;
    int eh = lane >> 5;            // edge within pair
    int lf = lane & 31;            // feature chunk (4 feats)
    int rot = lf >> 3;             // bank rotation
    for (int base2 = wv * 8; base2 < cnt; base2 += 64) {
        int pk[4];
        float msk[4];
        #pragma unroll
        for (int u = 0; u < 4; ++u) {
            int e = base2 + 2 * u + eh;
            bool ok = (e < cnt);
            int ee = ok ? e : 0;
            pk[u] = sorted ? ebuf[ee] : packed[beg + ee];
            msk[u] = ok ? 1.f : 0.f;
        }
        ushort4 v[4];
        #pragma unroll
        for (int u = 0; u < 4; ++u)
            v[u] = xr[(size_t)(pk[u] & 0x1FFFF) * 32 + lf];
        #pragma unroll
        for (int u = 0; u < 4; ++u) {
            float* row = accum[pk[u] >> 17];
            #pragma unroll
            for (int j = 0; j < 4; ++j) {
                int c = (j + rot) & 3;
                unsigned short h = (c == 0) ? v[u].x : (c == 1) ? v[u].y
                                 : (c == 2) ? v[u].z : v[u].w;
                atomicAdd(&row[4 * lf + c], msk[u] * bf2f(h));
            }
        }
    }
    __syncthreads();

    // writeout: bf16(accum * inorm) into strided aggh slots
    int nn = min(BNODES, N - node0);
    for (int i = tid; i < nn * 32; i += 512) {
        int r = i >> 5, ch = i & 31;
        float s = rsqrtf((float)max(ndeg[r], 1));
        float4 a = reinterpret_cast<float4*>(accum[r])[ch];
        ushort4 o;
        o.x = f2bf(a.x * s); o.y = f2bf(a.y * s);
        o.z = f2bf(a.z * s); o.w = f2bf(a.w * s);
        *reinterpret_cast<ushort4*>(aggh + (size_t)(node0 + r) * 256 + ch * 4) = o;
    }
}

// ---------------- MFMA projection: out = aggh @ W + b, in-place over d_out ----------------
__global__ __launch_bounds__(256)
void mm_mfma_kernel(const unsigned short* __restrict__ aggh, float* outp,
                    const unsigned short* __restrict__ Wt, const float* __restrict__ b, int N) {
    __shared__ unsigned short Al[NFEAT * NFEAT];   // 32 KiB
    __shared__ unsigned short Bl[NFEAT * NFEAT];   // 32 KiB  (Wt: [col][k])
    int tid = threadIdx.x;
    int r0 = blockIdx.x * 128;

    for (int c = tid; c < 2048; c += 256) {
        int col = c >> 4, sub = c & 15;
        int slot = sub ^ (col & 7);
        *reinterpret_cast<uint4*>(reinterpret_cast<char*>(Bl) + col * 256 + slot * 16) =
            *reinterpret_cast<const uint4*>(reinterpret_cast<const char*>(Wt) + c * 16);
    }
    for (int c = tid; c < 2048; c += 256) {
        int row = c >> 4, sub = c & 15;
        int grow = min(r0 + row, N - 1);
        int slot = sub ^ (row & 7);
        *reinterpret_cast<uint4*>(reinterpret_cast<char*>(Al) + row * 256 + slot * 16) =
            *reinterpret_cast<const uint4*>(reinterpret_cast<const char*>(aggh) +
                                            (size_t)grow * 512 + sub * 16);
    }
    __syncthreads();

    int lane = tid & 63;
    int wave = tid >> 6;
    int wr = wave >> 1, wc = wave & 1;
    int lrow = lane & 15, hi = lane >> 4;

    f32x4 zero = {0.f, 0.f, 0.f, 0.f};
    f32x4 acc[4][4];
    #pragma unroll
    for (int rt = 0; rt < 4; ++rt)
        #pragma unroll
        for (int ct = 0; ct < 4; ++ct) acc[rt][ct] = zero;

    #pragma unroll
    for (int ks = 0; ks < 4; ++ks) {
        int chunk = ks * 4 + hi;
        bf16x8 af[4], bfr[4];
        #pragma unroll
        for (int rt = 0; rt < 4; ++rt) {
            int row = wr * 64 + rt * 16 + lrow;
            af[rt] = *reinterpret_cast<bf16x8*>(reinterpret_cast<char*>(Al) + row * 256 +
                                                ((chunk ^ (row & 7)) * 16));
        }
        #pragma unroll
        for (int ct = 0; ct < 4; ++ct) {
            int col = wc * 64 + ct * 16 + lrow;
            bfr[ct] = *reinterpret_cast<bf16x8*>(reinterpret_cast<char*>(Bl) + col * 256 +
                                                 ((chunk ^ (col & 7)) * 16));
        }
        #pragma unroll
        for (int rt = 0; rt < 4; ++rt)
            #pragma unroll
            for (int ct = 0; ct < 4; ++ct)
                acc[rt][ct] = __builtin_amdgcn_mfma_f32_16x16x32_bf16(af[rt], bfr[ct],
                                                                     acc[rt][ct], 0, 0, 0);
    }

    #pragma unroll
    for (int ct = 0; ct < 4; ++ct) {
        int col = wc * 64 + ct * 16 + lrow;
        float bias = b[col];
        #pragma unroll
        for (int rt = 0; rt < 4; ++rt) {
            int rbase = r0 + wr * 64 + rt * 16 + hi * 4;
            #pragma unroll
            for (int q = 0; q < 4; ++q) {
                int row = rbase + q;
                if (row < N) outp[(size_t)row * NFEAT + col] = acc[rt][ct][q] + bias;
            }
        }
    }
}

extern "C" void kernel_launch(void* const* d_in, const int* in_sizes, int n_in,
                              void* d_out, int out_size, void* d_ws, size_t ws_size,
                              hipStream_t stream) {
    const float* x   = (const float*)d_in[0];
    const int*   src = (const int*)d_in[1];
    const int*   dst = (const int*)d_in[2];
    const float* W   = (const float*)d_in[3];
    const float* b   = (const float*)d_in[4];

    const int N = in_sizes[0] / NFEAT;   // 100000
    const int E = in_sizes[1];           // 1600000
    float* out = (float*)d_out;

    const int NB = (N + BNODES - 1) >> BSHIFT;   // 782

    // ws layout (ints unless noted):
    // [out_deg N][bucket_cnt NBMAX]  <- zeroed together
    // [bucket_base NBMAX+1][bucket_cursor NBMAX][packed E][Wt 16384 bf16][xh N*128 bf16]
    int* out_deg       = (int*)d_ws;
    int* bucket_cnt    = out_deg + N;
    int* bucket_base   = bucket_cnt + NBMAX;
    int* bucket_cursor = bucket_base + (NBMAX + 1);
    int* packed        = bucket_cursor + NBMAX;
    unsigned short* Wt = (unsigned short*)(packed + E);
    unsigned short* xh = Wt + NFEAT * NFEAT;

    hipMemsetAsync(d_ws, 0, (size_t)(N + NBMAX) * sizeof(int), stream);

    int nchunk = (E + CHUNK - 1) / CHUNK;        // 196
    edge_count_kernel<<<nchunk, 256, 0, stream>>>(src, dst, E, out_deg, bucket_cnt, NB);
    bucket_scan_kernel<<<1, 1024, 0, stream>>>(bucket_cnt, bucket_base, bucket_cursor, NB);
    partition_kernel<<<nchunk, 256, 0, stream>>>(src, dst, E, bucket_cursor, packed, NB);

    int cast_threads = N * 32 + NFEAT * NFEAT;
    cast_kernel<<<(cast_threads + 255) / 256, 256, 0, stream>>>(x, out_deg, xh, W, Wt, N);

    unsigned short* aggh = (unsigned short*)d_out;   // strided: node i payload at byte i*512
    bucket_agg_kernel<<<NB, 512, 0, stream>>>(xh, packed, bucket_base, aggh, N);

    mm_mfma_kernel<<<(N + 127) / 128, 256, 0, stream>>>(aggh, out, Wt, b, N);
}

// Round 8
// 238.919 us; speedup vs baseline: 6.2656x; 6.2656x over previous
//
#include <hip/hip_runtime.h>

#define NFEAT 128
#define BSHIFT 6
#define BNODES 64             // dst nodes per bucket
#define NBMAX 2048            // max buckets (N <= 131072)
#define CHUNK 8192            // edges per counting/partition block
#define EBUF_CAP 1536         // per-bucket edge capacity per pass (mean ~1024, sigma ~32)

typedef __attribute__((ext_vector_type(8))) short bf16x8;
typedef __attribute__((ext_vector_type(4))) float f32x4;

__device__ inline unsigned short f2bf(float f) {            // RNE
    unsigned u = __float_as_uint(f);
    u += 0x7FFF + ((u >> 16) & 1);
    return (unsigned short)(u >> 16);
}
__device__ inline float bf2f(unsigned short h) {
    return __uint_as_float((unsigned)h << 16);
}

// ---------------- per-bucket edge counts (dst only) ----------------
__global__ __launch_bounds__(256)
void edge_count_kernel(const int* __restrict__ dst, int E,
                       int* __restrict__ bucket_cnt, int NB) {
    __shared__ int cnt[NBMAX];
    for (int i = threadIdx.x; i < NB; i += 256) cnt[i] = 0;
    __syncthreads();
    int base = blockIdx.x * CHUNK;
    int end = min(base + CHUNK, E);
    for (int j = base + threadIdx.x; j < end; j += 256)
        atomicAdd(&cnt[dst[j] >> BSHIFT], 1);
    __syncthreads();
    for (int i = threadIdx.x; i < NB; i += 256)
        if (cnt[i]) atomicAdd(&bucket_cnt[i], cnt[i]);
}

// ---------------- scan bucket counts -> base & cursor (1 block; 2 bins/thread) ----------------
__global__ __launch_bounds__(1024)
void bucket_scan_kernel(const int* __restrict__ bucket_cnt,
                        int* __restrict__ bucket_base,
                        int* __restrict__ bucket_cursor, int NB) {
    __shared__ int sa[1024], sb[1024];
    int t = threadIdx.x;
    int i0 = 2 * t, i1 = 2 * t + 1;
    int v0 = (i0 < NB) ? bucket_cnt[i0] : 0;
    int v1 = (i1 < NB) ? bucket_cnt[i1] : 0;
    int p = v0 + v1;
    sa[t] = p;
    __syncthreads();
    int* s = sa; int* tt = sb;
    for (int d = 1; d < 1024; d <<= 1) {
        tt[t] = s[t] + (t >= d ? s[t - d] : 0);
        __syncthreads();
        int* tmp = s; s = tt; tt = tmp;
    }
    int excl = s[t] - p;
    if (i0 < NB) { bucket_base[i0] = excl;      bucket_cursor[i0] = excl; }
    if (i1 < NB) { bucket_base[i1] = excl + v0; bucket_cursor[i1] = excl + v0; }
    if (t == 1023) bucket_base[NB] = s[1023];   // = E
}

// ---------------- partition edges into dst-bucket-ordered packed array (+ out_deg) ------------
// packed = ((dst & 63) << 17) | src   (src < 2^17)
__global__ __launch_bounds__(256)
void partition_kernel(const int* __restrict__ src, const int* __restrict__ dst, int E,
                      int* __restrict__ bucket_cursor, int* __restrict__ packed,
                      int* __restrict__ out_deg, int NB) {
    __shared__ int cnt[NBMAX];
    for (int i = threadIdx.x; i < NB; i += 256) cnt[i] = 0;
    __syncthreads();
    int base = blockIdx.x * CHUNK;
    int end = min(base + CHUNK, E);
    for (int j = base + threadIdx.x; j < end; j += 256)
        atomicAdd(&cnt[dst[j] >> BSHIFT], 1);
    __syncthreads();
    for (int i = threadIdx.x; i < NB; i += 256) {
        int c = cnt[i];
        cnt[i] = c ? atomicAdd(&bucket_cursor[i], c) : 0;   // becomes global run base
    }
    __syncthreads();
    for (int j = base + threadIdx.x; j < end; j += 256) {
        int sj = src[j];
        atomicAdd(&out_deg[sj], 1);
        int d = dst[j];
        int bb = d >> BSHIFT;
        int pos = atomicAdd(&cnt[bb], 1);
        packed[pos] = ((d & (BNODES - 1)) << 17) | sj;
    }
}

// ---------------- xh = bf16(x * onorm); tail threads transpose-cast W ----------------
__global__ __launch_bounds__(256)
void cast_kernel(const float* __restrict__ x, const int* __restrict__ out_deg,
                 unsigned short* __restrict__ xh,
                 const float* __restrict__ W, unsigned short* __restrict__ Wt, int N) {
    int t = blockIdx.x * 256 + threadIdx.x;
    int total = N * (NFEAT / 4);
    if (t < total) {
        int row = t >> 5;                       // 32 chunks per row
        float sc = rsqrtf((float)max(out_deg[row], 1));
        float4 v = reinterpret_cast<const float4*>(x)[t];
        ushort4 o;
        o.x = f2bf(v.x * sc); o.y = f2bf(v.y * sc);
        o.z = f2bf(v.z * sc); o.w = f2bf(v.w * sc);
        reinterpret_cast<ushort4*>(xh)[t] = o;
    } else {
        int i = t - total;
        if (i < NFEAT * NFEAT) {
            int col = i >> 7, k = i & 127;
            Wt[i] = f2bf(W[k * NFEAT + col]);   // Wt[col][k]
        }
    }
}

// ---------------- fused: per-bucket node-sort + register gather-agg + MFMA projection --------
// One block (256 thr) per 64-dst-node bucket. Counting-sort bucket edges by node in LDS
// (indices only), half-wave per node gathers xh rows into REGISTER float4 acc (8-wide ILP),
// writes swizzled bf16 A-tile to LDS, then 4 waves MFMA vs Wt (global, L2-hot) -> f32 out.
__global__ __launch_bounds__(256)
void agg_mm_kernel(const unsigned short* __restrict__ xh, const int* __restrict__ packed,
                   const int* __restrict__ bucket_base, const unsigned short* __restrict__ Wt,
                   const float* __restrict__ bias, float* __restrict__ outp, int N) {
    __shared__ unsigned short Atile[BNODES * NFEAT];   // 16 KiB, XOR-swizzled rows
    __shared__ int ebuf[EBUF_CAP];                     // 6 KiB (node-sorted packed edges)
    __shared__ int nhist[BNODES], nstart[BNODES], ncur[BNODES], ndeg[BNODES];
    __shared__ int ssa[BNODES], ssb[BNODES];

    int bkt = blockIdx.x;
    int node0 = bkt << BSHIFT;
    int beg = bucket_base[bkt];
    int end = bucket_base[bkt + 1];
    int tid = threadIdx.x;
    int hw = tid >> 5;          // half-wave 0..7
    int lf = tid & 31;          // feature chunk (4 feats)

    float4 acc[8];
    #pragma unroll
    for (int k = 0; k < 8; ++k) acc[k] = make_float4(0.f, 0.f, 0.f, 0.f);
    if (tid < BNODES) ndeg[tid] = 0;

    const ushort4* xr = reinterpret_cast<const ushort4*>(xh);

    for (int cbeg = beg; cbeg < end; cbeg += EBUF_CAP) {
        int ccnt = min(end - cbeg, EBUF_CAP);
        if (tid < BNODES) nhist[tid] = 0;
        __syncthreads();
        for (int i = tid; i < ccnt; i += 256)
            atomicAdd(&nhist[packed[cbeg + i] >> 17], 1);
        __syncthreads();
        // exclusive scan of 64 bins (threads 0..63; barriers uniform)
        int v = (tid < BNODES) ? nhist[tid] : 0;
        if (tid < BNODES) ssa[tid] = v;
        __syncthreads();
        int* s = ssa; int* t = ssb;
        for (int d = 1; d < BNODES; d <<= 1) {
            if (tid < BNODES) t[tid] = s[tid] + (tid >= d ? s[tid - d] : 0);
            __syncthreads();
            int* tmp = s; s = t; t = tmp;
        }
        if (tid < BNODES) {
            int excl = s[tid] - v;
            nstart[tid] = excl;
            ncur[tid] = excl;
            ndeg[tid] += v;
        }
        __syncthreads();
        for (int i = tid; i < ccnt; i += 256) {
            int p = packed[cbeg + i];
            int pos = atomicAdd(&ncur[p >> 17], 1);
            ebuf[pos] = p;
        }
        __syncthreads();
        // gather: half-wave hw owns nodes hw + 8*kn (kn = 0..7)
        #pragma unroll
        for (int kn = 0; kn < 8; ++kn) {
            int n = hw + 8 * kn;
            int s0 = nstart[n];
            int c = nhist[n];
            for (int i = 0; i < c; i += 8) {
                int sidx[8]; float msk[8];
                #pragma unroll
                for (int u = 0; u < 8; ++u) {          // phase 1: LDS index reads (broadcast)
                    int j = i + u;
                    bool ok = (j < c);
                    sidx[u] = ok ? (ebuf[s0 + j] & 0x1FFFF) : 0;
                    msk[u] = ok ? 1.f : 0.f;
                }
                ushort4 vv[8];
                #pragma unroll
                for (int u = 0; u < 8; ++u)            // phase 2: 8 independent gathers
                    vv[u] = xr[(size_t)sidx[u] * 32 + lf];
                #pragma unroll
                for (int u = 0; u < 8; ++u) {          // phase 3: masked accumulate
                    acc[kn].x = fmaf(msk[u], bf2f(vv[u].x), acc[kn].x);
                    acc[kn].y = fmaf(msk[u], bf2f(vv[u].y), acc[kn].y);
                    acc[kn].z = fmaf(msk[u], bf2f(vv[u].z), acc[kn].z);
                    acc[kn].w = fmaf(msk[u], bf2f(vv[u].w), acc[kn].w);
                }
            }
        }
        __syncthreads();    // nhist/nstart consumed; safe to reuse next chunk
    }

    // write inorm-scaled bf16 rows into swizzled A-tile
    #pragma unroll
    for (int kn = 0; kn < 8; ++kn) {
        int n = hw + 8 * kn;
        float sc = rsqrtf((float)max(ndeg[n], 1));
        ushort4 o;
        o.x = f2bf(acc[kn].x * sc); o.y = f2bf(acc[kn].y * sc);
        o.z = f2bf(acc[kn].z * sc); o.w = f2bf(acc[kn].w * sc);
        int sub = lf >> 1, h8 = lf & 1;
        char* pA = reinterpret_cast<char*>(Atile) + n * 256 + ((sub ^ (n & 7)) * 16) + h8 * 8;
        *reinterpret_cast<ushort4*>(pA) = o;
    }
    __syncthreads();

    // MFMA: 4 waves; wave = (h2: 32-row half) x (c2: 64-col half); acc2[2][4]
    int lane = tid & 63;
    int wave = tid >> 6;
    int h2 = wave & 1, c2 = wave >> 1;
    int lrow = lane & 15, hi = lane >> 4;

    f32x4 zero = {0.f, 0.f, 0.f, 0.f};
    f32x4 acc2[2][4];
    #pragma unroll
    for (int rt = 0; rt < 2; ++rt)
        #pragma unroll
        for (int ct = 0; ct < 4; ++ct) acc2[rt][ct] = zero;

    #pragma unroll
    for (int ks = 0; ks < 4; ++ks) {
        int chunk = ks * 4 + hi;
        bf16x8 af[2], bf_[4];
        #pragma unroll
        for (int rt = 0; rt < 2; ++rt) {
            int row = h2 * 32 + rt * 16 + lrow;
            af[rt] = *reinterpret_cast<bf16x8*>(reinterpret_cast<char*>(Atile) + row * 256 +
                                                ((chunk ^ (row & 7)) * 16));
        }
        #pragma unroll
        for (int ct = 0; ct < 4; ++ct) {
            int col = c2 * 64 + ct * 16 + lrow;
            bf_[ct] = *reinterpret_cast<const bf16x8*>(Wt + col * NFEAT + chunk * 8);
        }
        #pragma unroll
        for (int rt = 0; rt < 2; ++rt)
            #pragma unroll
            for (int ct = 0; ct < 4; ++ct)
                acc2[rt][ct] = __builtin_amdgcn_mfma_f32_16x16x32_bf16(af[rt], bf_[ct],
                                                                      acc2[rt][ct], 0, 0, 0);
    }

    #pragma unroll
    for (int ct = 0; ct < 4; ++ct) {
        int col = c2 * 64 + ct * 16 + lrow;
        float bb = bias[col];
        #pragma unroll
        for (int rt = 0; rt < 2; ++rt) {
            int rb = h2 * 32 + rt * 16 + hi * 4;
            #pragma unroll
            for (int q = 0; q < 4; ++q) {
                int grow = node0 + rb + q;
                if (grow < N) outp[(size_t)grow * NFEAT + col] = acc2[rt][ct][q] + bb;
            }
        }
    }
}

extern "C" void kernel_launch(void* const* d_in, const int* in_sizes, int n_in,
                              void* d_out, int out_size, void* d_ws, size_t ws_size,
                              hipStream_t stream) {
    const float* x   = (const float*)d_in[0];
    const int*   src = (const int*)d_in[1];
    const int*   dst = (const int*)d_in[2];
    const float* W   = (const float*)d_in[3];
    const float* b   = (const float*)d_in[4];

    const int N = in_sizes[0] / NFEAT;   // 100000
    const int E = in_sizes[1];           // 1600000
    float* out = (float*)d_out;

    const int NB = (N + BNODES - 1) >> BSHIFT;   // 1563

    // ws layout (ints unless noted):
    // [out_deg N][bucket_cnt NBMAX]  <- zeroed together
    // [bucket_base NBMAX+1][bucket_cursor NBMAX][packed E][Wt 16384 bf16][xh N*128 bf16]
    int* out_deg       = (int*)d_ws;
    int* bucket_cnt    = out_deg + N;
    int* bucket_base   = bucket_cnt + NBMAX;
    int* bucket_cursor = bucket_base + (NBMAX + 1);
    int* packed        = bucket_cursor + NBMAX;
    unsigned short* Wt = (unsigned short*)(packed + E);
    unsigned short* xh = Wt + NFEAT * NFEAT;

    hipMemsetAsync(d_ws, 0, (size_t)(N + NBMAX) * sizeof(int), stream);

    int nchunk = (E + CHUNK - 1) / CHUNK;        // 196
    edge_count_kernel<<<nchunk, 256, 0, stream>>>(dst, E, bucket_cnt, NB);
    bucket_scan_kernel<<<1, 1024, 0, stream>>>(bucket_cnt, bucket_base, bucket_cursor, NB);
    partition_kernel<<<nchunk, 256, 0, stream>>>(src, dst, E, bucket_cursor, packed,
                                                 out_deg, NB);

    int cast_threads = N * 32 + NFEAT * NFEAT;
    cast_kernel<<<(cast_threads + 255) / 256, 256, 0, stream>>>(x, out_deg, xh, W, Wt, N);

    agg_mm_kernel<<<NB, 256, 0, stream>>>(xh, packed, bucket_base, Wt, b, out, N);
}